// Round 1
// baseline (4452.208 us; speedup 1.0000x reference)
//
#include <hip/hip_runtime.h>

using u16 = unsigned short;
using u32 = unsigned int;

typedef _Float16 f16x2 __attribute__((ext_vector_type(2)));
typedef _Float16 f16x8 __attribute__((ext_vector_type(8)));
typedef float    f32x4 __attribute__((ext_vector_type(4)));

__device__ __forceinline__ u16 f16bits(float x) {
  union { _Float16 h; u16 u; } r; r.h = (_Float16)x; return r.u;
}
__device__ __forceinline__ float h2f(u16 v) {
  union { u16 u; _Float16 h; } r; r.u = v; return (float)r.h;
}
__device__ __forceinline__ u32 pack2(float a, float b) {
  union { f16x2 h; u32 u; } r; r.h.x = (_Float16)a; r.h.y = (_Float16)b; return r.u;
}
__device__ __forceinline__ float fdot2a(u32 a, u32 b, float c) {
  union { u32 u; f16x2 h; } ua, ub; ua.u = a; ub.u = b;
#if __has_builtin(__builtin_amdgcn_fdot2)
  return __builtin_amdgcn_fdot2(ua.h, ub.h, c, false);
#else
  return c + (float)ua.h.x * (float)ub.h.x + (float)ua.h.y * (float)ub.h.y;
#endif
}
__device__ __forceinline__ float sigmoidf_(float x) { return 1.0f / (1.0f + __expf(-x)); }
__device__ __forceinline__ float tanhf_(float x)    { return 1.0f - 2.0f / (__expf(2.0f * x) + 1.0f); }

__device__ __forceinline__ f16x8 lds16(const u16* p) {
  union { uint4 u; f16x8 h; } r; r.u = *(const uint4*)p; return r.h;
}

// ---------------- prep: build f16 weight layouts + zero state ----------------
// WxT[n][k]  : [1024][256] f16, transposed input-proj weights (n = gate*256+col)
// Whp[kk][j] : [128][1024] u32, f16x2 pairs (W_h[2kk][j], W_h[2kk+1][j])
// h16s       : [128][128] u32 (f16x2 pairs of h state), zeroed
// c_s        : [128][256] f32 c state, zeroed
__global__ void lstm_prep(const float* __restrict__ Wxi, const float* __restrict__ Wxf,
                          const float* __restrict__ Wxg, const float* __restrict__ Wxo,
                          const float* __restrict__ Whi, const float* __restrict__ Whf,
                          const float* __restrict__ Whg, const float* __restrict__ Who,
                          u16* __restrict__ WxT, u32* __restrict__ Whp,
                          u32* __restrict__ h16s, float* __restrict__ c_s) {
  int idx = blockIdx.x * 256 + threadIdx.x;
  if (idx < 262144) {                       // WxT
    int n = idx >> 8, k = idx & 255;
    int g = n >> 8;
    const float* W = (g == 0) ? Wxi : (g == 1) ? Wxf : (g == 2) ? Wxg : Wxo;
    WxT[idx] = f16bits(W[k * 256 + (n & 255)]);
  } else if (idx < 262144 + 131072) {       // Whp
    int i2 = idx - 262144;
    int kk = i2 >> 10, jj = i2 & 1023;
    int g = jj >> 8, col = jj & 255;
    const float* W = (g == 0) ? Whi : (g == 1) ? Whf : (g == 2) ? Whg : Who;
    u32 lo = f16bits(W[(2 * kk) * 256 + col]);
    u32 hi = f16bits(W[(2 * kk + 1) * 256 + col]);
    Whp[i2] = lo | (hi << 16);
  } else if (idx < 262144 + 131072 + 16384) {
    h16s[idx - 393216] = 0u;
  } else if (idx < 262144 + 131072 + 16384 + 32768) {
    c_s[idx - 409600] = 0.0f;
  }
}

// ---------------- input-projection GEMM --------------------------------------
// gates16[m][n] f16, m = b*Tc + tc (chunk-local flat row), n in [0,1024)
// A = x rows (fp32 -> f16 on the fly), B = WxT. 128x128 tile, BK=64, 4 waves.
__global__ __launch_bounds__(256) void proj_gemm(
    const float* __restrict__ x, const u16* __restrict__ WxT,
    u16* __restrict__ gates, const float* __restrict__ bi,
    const float* __restrict__ bf, const float* __restrict__ bg,
    const float* __restrict__ bo, int t0, int tcShift) {
  __shared__ u16 Al[128 * 72];   // +8 f16 pad -> 2-way-free bank pattern
  __shared__ u16 Bl[128 * 72];
  const int tid = threadIdx.x;
  const int lane = tid & 63, wv = tid >> 6;
  const int wr = wv >> 1, wc = wv & 1;
  const int m0 = blockIdx.x * 128, n0 = blockIdx.y * 128;
  const int tcMask = (1 << tcShift) - 1;
  f32x4 acc[4][4] = {};
  for (int k0 = 0; k0 < 256; k0 += 64) {
    // stage A: 128 rows x 64 cols fp32->f16
#pragma unroll
    for (int p = 0; p < 8; ++p) {
      int flat = p * 256 + tid;
      int r = flat >> 4, cc = flat & 15;
      int m = m0 + r;
      int b = m >> tcShift, tc = m & tcMask;
      const float4 xv = *(const float4*)(x + (size_t)(b * 1024 + t0 + tc) * 256 + k0 + cc * 4);
      uint2 w2 = make_uint2(pack2(xv.x, xv.y), pack2(xv.z, xv.w));
      *(uint2*)&Al[r * 72 + cc * 4] = w2;
    }
    // stage B (already f16, already transposed): Bl[n][k]
#pragma unroll
    for (int p = 0; p < 8; ++p) {
      int flat = p * 256 + tid;
      int r = flat >> 4, cc = flat & 15;
      uint2 w2 = *(const uint2*)(WxT + (size_t)(n0 + r) * 256 + k0 + cc * 4);
      *(uint2*)&Bl[r * 72 + cc * 4] = w2;
    }
    __syncthreads();
#pragma unroll
    for (int kk = 0; kk < 64; kk += 32) {
      f16x8 af[4], bfr[4];
#pragma unroll
      for (int i = 0; i < 4; ++i) {
        af[i]  = lds16(&Al[(wr * 64 + i * 16 + (lane & 15)) * 72 + kk + (lane >> 4) * 8]);
        bfr[i] = lds16(&Bl[(wc * 64 + i * 16 + (lane & 15)) * 72 + kk + (lane >> 4) * 8]);
      }
#pragma unroll
      for (int mi = 0; mi < 4; ++mi)
#pragma unroll
        for (int ni = 0; ni < 4; ++ni)
          acc[mi][ni] = __builtin_amdgcn_mfma_f32_16x16x32_f16(af[mi], bfr[ni], acc[mi][ni], 0, 0, 0);
    }
    __syncthreads();
  }
  // epilogue: +bias, f16 store
#pragma unroll
  for (int ni = 0; ni < 4; ++ni) {
    int n = n0 + wc * 64 + ni * 16 + (lane & 15);
    int g = n >> 8;
    const float* bp = (g == 0) ? bi : (g == 1) ? bf : (g == 2) ? bg : bo;
    float bias = bp[n & 255];
#pragma unroll
    for (int mi = 0; mi < 4; ++mi) {
#pragma unroll
      for (int ri = 0; ri < 4; ++ri) {
        int m = m0 + wr * 64 + mi * 16 + (lane >> 4) * 4 + ri;
        gates[(size_t)m * 1024 + n] = f16bits(acc[mi][ni][ri] + bias);
      }
    }
  }
}

// ---------------- persistent per-batch recurrence ----------------------------
// 1024 threads, thread j owns output column j (j = gate*256+col).
// W_h[:,j]: pairs kk 0..91 in VGPRs, kk 92..127 in LDS rows [36][1024].
__global__ __launch_bounds__(1024) void lstm_rec(
    const u32* __restrict__ Whp, const u16* __restrict__ gates,
    u32* __restrict__ h16s, float* __restrict__ c_s,
    const float* __restrict__ Why, const float* __restrict__ by,
    float* __restrict__ out, int Tc, int last) {
  extern __shared__ unsigned char smem[];
  u32*   W2L  = (u32*)smem;                          // [36][1024] = 147456 B
  float* zbuf = (float*)(smem + 36 * 4096);          // [1024]     =   4096 B
  u32*   hbuf = (u32*)(smem + 36 * 4096 + 4096);     // [128]      =    512 B
  const int b = blockIdx.x, j = threadIdx.x;

  u32 wreg[92];
#pragma unroll
  for (int q = 0; q < 92; ++q) wreg[q] = Whp[q * 1024 + j];
  for (int q = 0; q < 36; ++q) W2L[q * 1024 + j] = Whp[(92 + q) * 1024 + j];
  if (j < 128) hbuf[j] = h16s[b * 128 + j];
  float c = 0.0f;
  if (j < 256) c = c_s[b * 256 + j];
  const u16* gxp = gates + (size_t)b * Tc * 1024 + j;
  u16 pre = gxp[0];
  __syncthreads();

  for (int tc = 0; tc < Tc; ++tc) {
    u16 cur = pre;
    if (tc + 1 < Tc) pre = gxp[(size_t)(tc + 1) * 1024];
    float acc0 = 0.0f, acc1 = 0.0f;
    const uint4* h4p = (const uint4*)hbuf;
#pragma unroll
    for (int q = 0; q < 23; ++q) {          // register-resident weights
      uint4 hq = h4p[q];
      acc0 = fdot2a(hq.x, wreg[4 * q + 0], acc0);
      acc1 = fdot2a(hq.y, wreg[4 * q + 1], acc1);
      acc0 = fdot2a(hq.z, wreg[4 * q + 2], acc0);
      acc1 = fdot2a(hq.w, wreg[4 * q + 3], acc1);
    }
#pragma unroll
    for (int q = 23; q < 32; ++q) {         // LDS-resident weights
      uint4 hq = h4p[q];
      const int r = (q - 23) * 4;
      acc0 = fdot2a(hq.x, W2L[(r + 0) * 1024 + j], acc0);
      acc1 = fdot2a(hq.y, W2L[(r + 1) * 1024 + j], acc1);
      acc0 = fdot2a(hq.z, W2L[(r + 2) * 1024 + j], acc0);
      acc1 = fdot2a(hq.w, W2L[(r + 3) * 1024 + j], acc1);
    }
    zbuf[j] = acc0 + acc1 + h2f(cur);
    __syncthreads();
    if (j < 256) {
      float zi = zbuf[j], zf = zbuf[j + 256], zg = zbuf[j + 512], zo = zbuf[j + 768];
      float i_ = sigmoidf_(zi), f_ = sigmoidf_(zf), g_ = tanhf_(zg), o_ = sigmoidf_(zo);
      c = f_ * c + i_ * g_;
      float h_ = o_ * tanhf_(c);
      ((u16*)hbuf)[j] = f16bits(h_);
    }
    __syncthreads();
  }

  if (j < 128) h16s[b * 128 + j] = hbuf[j];
  if (j < 256) c_s[b * 256 + j] = c;

  if (last && j < 128) {                    // y = h_T @ W_hy + b_y
    float acc = by[j];
    const u16* hh = (const u16*)hbuf;
#pragma unroll 8
    for (int k = 0; k < 256; ++k) acc += h2f(hh[k]) * Why[k * 128 + j];
    out[b * 128 + j] = acc;
  }
}

extern "C" void kernel_launch(void* const* d_in, const int* in_sizes, int n_in,
                              void* d_out, int out_size, void* d_ws, size_t ws_size,
                              hipStream_t stream) {
  const float* x   = (const float*)d_in[0];
  const float* Wxi = (const float*)d_in[1];
  const float* Whi = (const float*)d_in[2];
  const float* b_i = (const float*)d_in[3];
  const float* Wxf = (const float*)d_in[4];
  const float* Whf = (const float*)d_in[5];
  const float* b_f = (const float*)d_in[6];
  const float* Wxg = (const float*)d_in[7];
  const float* Whg = (const float*)d_in[8];
  const float* b_g = (const float*)d_in[9];
  const float* Wxo = (const float*)d_in[10];
  const float* Who = (const float*)d_in[11];
  const float* b_o = (const float*)d_in[12];
  const float* Why = (const float*)d_in[13];
  const float* b_y = (const float*)d_in[14];
  float* out = (float*)d_out;

  // choose T-chunk so gates buffer + weight/state tables fit the workspace
  int Tc = 256;
  while (Tc > 32 && (size_t)128 * Tc * 1024 * 2 + 1245184ull > ws_size) Tc >>= 1;
  const int tcShift = __builtin_ctz((unsigned)Tc);
  const int nch = 1024 / Tc;

  char* wsb = (char*)d_ws;
  const size_t gbytes = (size_t)128 * Tc * 1024 * 2;
  u16*   gates16 = (u16*)wsb;
  u16*   WxT     = (u16*)(wsb + gbytes);
  u32*   Whp     = (u32*)(wsb + gbytes + 524288);
  u32*   h16s    = (u32*)(wsb + gbytes + 1048576);
  float* c_s     = (float*)(wsb + gbytes + 1048576 + 65536);

  (void)hipFuncSetAttribute((const void*)lstm_rec,
                            hipFuncAttributeMaxDynamicSharedMemorySize, 152064);

  lstm_prep<<<1728, 256, 0, stream>>>(Wxi, Wxf, Wxg, Wxo, Whi, Whf, Whg, Who,
                                      WxT, Whp, h16s, c_s);
  for (int ci = 0; ci < nch; ++ci) {
    int t0 = ci * Tc;
    proj_gemm<<<dim3(Tc, 8), 256, 0, stream>>>(x, WxT, gates16, b_i, b_f, b_g, b_o,
                                               t0, tcShift);
    lstm_rec<<<128, 1024, 152064, stream>>>(Whp, gates16, h16s, c_s, Why, b_y, out,
                                            Tc, (ci == nch - 1) ? 1 : 0);
  }
}

// Round 2
// 2253.770 us; speedup vs baseline: 1.9754x; 1.9754x over previous
//
#include <hip/hip_runtime.h>

using u16 = unsigned short;
using u32 = unsigned int;

typedef _Float16 f16x2 __attribute__((ext_vector_type(2)));
typedef _Float16 f16x8 __attribute__((ext_vector_type(8)));
typedef float    f32x4 __attribute__((ext_vector_type(4)));

__device__ __forceinline__ u16 f16bits(float x) {
  union { _Float16 h; u16 u; } r; r.h = (_Float16)x; return r.u;
}
__device__ __forceinline__ float h2f(u16 v) {
  union { u16 u; _Float16 h; } r; r.u = v; return (float)r.h;
}
__device__ __forceinline__ u32 pack2(float a, float b) {
  union { f16x2 h; u32 u; } r; r.h.x = (_Float16)a; r.h.y = (_Float16)b; return r.u;
}
__device__ __forceinline__ float fdot2a(u32 a, u32 b, float c) {
  union { u32 u; f16x2 h; } ua, ub; ua.u = a; ub.u = b;
#if __has_builtin(__builtin_amdgcn_fdot2)
  return __builtin_amdgcn_fdot2(ua.h, ub.h, c, false);
#else
  return c + (float)ua.h.x * (float)ub.h.x + (float)ua.h.y * (float)ub.h.y;
#endif
}
__device__ __forceinline__ float sigmoidf_(float x) { return 1.0f / (1.0f + __expf(-x)); }
__device__ __forceinline__ float tanhf_(float x)    { return 1.0f - 2.0f / (__expf(2.0f * x) + 1.0f); }

__device__ __forceinline__ f16x8 lds16(const u16* p) {
  union { uint4 u; f16x8 h; } r; r.u = *(const uint4*)p; return r.h;
}

// ---------------- prep: build f16 weight layouts + zero state ----------------
// WxT[n][k]   : [1024][256] f16, transposed input-proj weights
// Whpp4[i4][t]: [32][1024] uint4 — per-(rec-)thread gathered W_h pair groups.
//   thread t: w=t>>6, l=t&63, q=l>>4; col(cc)=w*64+(l&15)*4+cc; i4=cc*8+pp;
//   element e of uint4 = f16x2 pair kk = q*32+pp*4+e of column cc.
// h16s        : [128][128] u32 pairs of h state, zeroed
// c_s         : [128][256] f32, zeroed
__global__ void lstm_prep(const float* __restrict__ Wxi, const float* __restrict__ Wxf,
                          const float* __restrict__ Wxg, const float* __restrict__ Wxo,
                          const float* __restrict__ Whi, const float* __restrict__ Whf,
                          const float* __restrict__ Whg, const float* __restrict__ Who,
                          u16* __restrict__ WxT, u32* __restrict__ Whpp,
                          u32* __restrict__ h16s, float* __restrict__ c_s) {
  int idx = blockIdx.x * 256 + threadIdx.x;
  if (idx < 262144) {                       // WxT
    int n = idx >> 8, k = idx & 255;
    int g = n >> 8;
    const float* W = (g == 0) ? Wxi : (g == 1) ? Wxf : (g == 2) ? Wxg : Wxo;
    WxT[idx] = f16bits(W[k * 256 + (n & 255)]);
  } else if (idx < 262144 + 131072) {       // Whpp (u32-granular writes)
    int i2 = idx - 262144;
    int e = i2 & 3, tmp = i2 >> 2;
    int t = tmp & 1023, i4 = tmp >> 10;
    int cc = i4 >> 3, pp = i4 & 7;
    int w = t >> 6, l = t & 63, q = l >> 4;
    int j = w * 64 + (l & 15) * 4 + cc;
    int kk = q * 32 + pp * 4 + e;
    int g = j >> 8, col = j & 255;
    const float* W = (g == 0) ? Whi : (g == 1) ? Whf : (g == 2) ? Whg : Who;
    u32 lo = f16bits(W[(2 * kk) * 256 + col]);
    u32 hi = f16bits(W[(2 * kk + 1) * 256 + col]);
    Whpp[i2] = lo | (hi << 16);
  } else if (idx < 262144 + 131072 + 16384) {
    h16s[idx - 393216] = 0u;
  } else if (idx < 262144 + 131072 + 16384 + 32768) {
    c_s[idx - 409600] = 0.0f;
  }
}

// ---------------- input-projection GEMM (unchanged) --------------------------
__global__ __launch_bounds__(256) void proj_gemm(
    const float* __restrict__ x, const u16* __restrict__ WxT,
    u16* __restrict__ gates, const float* __restrict__ bi,
    const float* __restrict__ bf, const float* __restrict__ bg,
    const float* __restrict__ bo, int t0, int tcShift) {
  __shared__ u16 Al[128 * 72];
  __shared__ u16 Bl[128 * 72];
  const int tid = threadIdx.x;
  const int lane = tid & 63, wv = tid >> 6;
  const int wr = wv >> 1, wc = wv & 1;
  const int m0 = blockIdx.x * 128, n0 = blockIdx.y * 128;
  const int tcMask = (1 << tcShift) - 1;
  f32x4 acc[4][4] = {};
  for (int k0 = 0; k0 < 256; k0 += 64) {
#pragma unroll
    for (int p = 0; p < 8; ++p) {
      int flat = p * 256 + tid;
      int r = flat >> 4, cc = flat & 15;
      int m = m0 + r;
      int b = m >> tcShift, tc = m & tcMask;
      const float4 xv = *(const float4*)(x + (size_t)(b * 1024 + t0 + tc) * 256 + k0 + cc * 4);
      uint2 w2 = make_uint2(pack2(xv.x, xv.y), pack2(xv.z, xv.w));
      *(uint2*)&Al[r * 72 + cc * 4] = w2;
    }
#pragma unroll
    for (int p = 0; p < 8; ++p) {
      int flat = p * 256 + tid;
      int r = flat >> 4, cc = flat & 15;
      uint2 w2 = *(const uint2*)(WxT + (size_t)(n0 + r) * 256 + k0 + cc * 4);
      *(uint2*)&Bl[r * 72 + cc * 4] = w2;
    }
    __syncthreads();
#pragma unroll
    for (int kk = 0; kk < 64; kk += 32) {
      f16x8 af[4], bfr[4];
#pragma unroll
      for (int i = 0; i < 4; ++i) {
        af[i]  = lds16(&Al[(wr * 64 + i * 16 + (lane & 15)) * 72 + kk + (lane >> 4) * 8]);
        bfr[i] = lds16(&Bl[(wc * 64 + i * 16 + (lane & 15)) * 72 + kk + (lane >> 4) * 8]);
      }
#pragma unroll
      for (int mi = 0; mi < 4; ++mi)
#pragma unroll
        for (int ni = 0; ni < 4; ++ni)
          acc[mi][ni] = __builtin_amdgcn_mfma_f32_16x16x32_f16(af[mi], bfr[ni], acc[mi][ni], 0, 0, 0);
    }
    __syncthreads();
  }
#pragma unroll
  for (int ni = 0; ni < 4; ++ni) {
    int n = n0 + wc * 64 + ni * 16 + (lane & 15);
    int g = n >> 8;
    const float* bp = (g == 0) ? bi : (g == 1) ? bf : (g == 2) ? bg : bo;
    float bias = bp[n & 255];
#pragma unroll
    for (int mi = 0; mi < 4; ++mi) {
#pragma unroll
      for (int ri = 0; ri < 4; ++ri) {
        int m = m0 + wr * 64 + mi * 16 + (lane >> 4) * 4 + ri;
        gates[(size_t)m * 1024 + n] = f16bits(acc[mi][ni][ri] + bias);
      }
    }
  }
}

// ---------------- persistent per-batch recurrence ----------------------------
// 1024 threads. thread (w=t>>6, l=t&63): 4 consecutive cols j=w*64+(l&15)*4+cc,
// K-quarter q=l>>4 (pairs q*32..q*32+31). 96 weight pairs in VGPR, 32 in LDS.
// Partial dots reduced across quarters via shfl_xor(16), shfl_xor(32).
__global__ __launch_bounds__(1024) void lstm_rec(
    const u32* __restrict__ Whpp, const u16* __restrict__ gates,
    u32* __restrict__ h16s, float* __restrict__ c_s,
    const float* __restrict__ Why, const float* __restrict__ by,
    float* __restrict__ out, int Tc, int last) {
  extern __shared__ unsigned char smem[];
  uint4* ldsW = (uint4*)smem;                       // [8][1024] uint4 = 131072 B
  u32*   hq   = (u32*)(smem + 131072);              // [2][4*36]  u32 = 1152 B (quarter stride 36: bank spread)
  float* zbuf = (float*)(smem + 131072 + 1152);     // [1024] f32     = 4096 B
  const int b = blockIdx.x, t = threadIdx.x;
  const int l = t & 63, w = t >> 6, q = l >> 4;
  const int jb = w * 64 + (l & 15) * 4;             // first of this thread's 4 cols

  // gather weights: 32 coalesced uint4 loads; 24 kept in VGPRs (pp<6), 8 to LDS
  u32 wreg[96];
  const uint4* Wp4 = (const uint4*)Whpp;
#pragma unroll
  for (int i4 = 0; i4 < 32; ++i4) {
    uint4 v = Wp4[i4 * 1024 + t];
    const int cc = i4 >> 3, pp = i4 & 7;
    if (pp < 6) {
      wreg[cc * 24 + pp * 4 + 0] = v.x;
      wreg[cc * 24 + pp * 4 + 1] = v.y;
      wreg[cc * 24 + pp * 4 + 2] = v.z;
      wreg[cc * 24 + pp * 4 + 3] = v.w;
    } else {
      ldsW[(cc * 2 + pp - 6) * 1024 + t] = v;
    }
  }
  if (t < 128) hq[(t >> 5) * 36 + (t & 31)] = h16s[b * 128 + t];
  float c = 0.0f;
  if (t < 256) c = c_s[b * 256 + t];
  const u16* gxp = gates + (size_t)b * Tc * 1024 + jb;
  int buf = 0;
  __syncthreads();

  for (int tc = 0; tc < Tc; ++tc) {
    uint2 gx = *(const uint2*)(gxp + (size_t)tc * 1024);   // 4 f16 gate pre-acts
    float acc0 = 0.f, acc1 = 0.f, acc2 = 0.f, acc3 = 0.f;
    const uint4* hb = (const uint4*)(hq + buf * 144 + q * 36);
#pragma unroll
    for (int u = 0; u < 8; ++u) {
      uint4 hv = hb[u];
      uint4 w0, w1, w2, w3;
      if (u < 6) {
        w0 = make_uint4(wreg[0 * 24 + u * 4], wreg[0 * 24 + u * 4 + 1], wreg[0 * 24 + u * 4 + 2], wreg[0 * 24 + u * 4 + 3]);
        w1 = make_uint4(wreg[1 * 24 + u * 4], wreg[1 * 24 + u * 4 + 1], wreg[1 * 24 + u * 4 + 2], wreg[1 * 24 + u * 4 + 3]);
        w2 = make_uint4(wreg[2 * 24 + u * 4], wreg[2 * 24 + u * 4 + 1], wreg[2 * 24 + u * 4 + 2], wreg[2 * 24 + u * 4 + 3]);
        w3 = make_uint4(wreg[3 * 24 + u * 4], wreg[3 * 24 + u * 4 + 1], wreg[3 * 24 + u * 4 + 2], wreg[3 * 24 + u * 4 + 3]);
      } else {
        w0 = ldsW[(0 * 2 + u - 6) * 1024 + t];
        w1 = ldsW[(1 * 2 + u - 6) * 1024 + t];
        w2 = ldsW[(2 * 2 + u - 6) * 1024 + t];
        w3 = ldsW[(3 * 2 + u - 6) * 1024 + t];
      }
      acc0 = fdot2a(hv.x, w0.x, acc0); acc0 = fdot2a(hv.y, w0.y, acc0);
      acc0 = fdot2a(hv.z, w0.z, acc0); acc0 = fdot2a(hv.w, w0.w, acc0);
      acc1 = fdot2a(hv.x, w1.x, acc1); acc1 = fdot2a(hv.y, w1.y, acc1);
      acc1 = fdot2a(hv.z, w1.z, acc1); acc1 = fdot2a(hv.w, w1.w, acc1);
      acc2 = fdot2a(hv.x, w2.x, acc2); acc2 = fdot2a(hv.y, w2.y, acc2);
      acc2 = fdot2a(hv.z, w2.z, acc2); acc2 = fdot2a(hv.w, w2.w, acc2);
      acc3 = fdot2a(hv.x, w3.x, acc3); acc3 = fdot2a(hv.y, w3.y, acc3);
      acc3 = fdot2a(hv.z, w3.z, acc3); acc3 = fdot2a(hv.w, w3.w, acc3);
    }
    // reduce partial sums across the 4 K-quarters (lanes l, l^16, l^32, l^48)
    acc0 += __shfl_xor(acc0, 16); acc0 += __shfl_xor(acc0, 32);
    acc1 += __shfl_xor(acc1, 16); acc1 += __shfl_xor(acc1, 32);
    acc2 += __shfl_xor(acc2, 16); acc2 += __shfl_xor(acc2, 32);
    acc3 += __shfl_xor(acc3, 16); acc3 += __shfl_xor(acc3, 32);
    if (l < 16) {
      float4 z4;
      z4.x = acc0 + h2f((u16)(gx.x & 0xffff));
      z4.y = acc1 + h2f((u16)(gx.x >> 16));
      z4.z = acc2 + h2f((u16)(gx.y & 0xffff));
      z4.w = acc3 + h2f((u16)(gx.y >> 16));
      *(float4*)&zbuf[jb] = z4;
    }
    __syncthreads();
    if (t < 256) {
      float zi = zbuf[t], zf = zbuf[t + 256], zg = zbuf[t + 512], zo = zbuf[t + 768];
      float i_ = sigmoidf_(zi), f_ = sigmoidf_(zf), g_ = tanhf_(zg), o_ = sigmoidf_(zo);
      c = f_ * c + i_ * g_;
      float h_ = o_ * tanhf_(c);
      const int kk = t >> 1, qq = kk >> 5, pp = kk & 31;
      ((u16*)(hq + (buf ^ 1) * 144))[(qq * 36 + pp) * 2 + (t & 1)] = f16bits(h_);
    }
    buf ^= 1;
    __syncthreads();
  }

  if (t < 128) h16s[b * 128 + t] = hq[buf * 144 + (t >> 5) * 36 + (t & 31)];
  if (t < 256) c_s[b * 256 + t] = c;

  if (last && t < 128) {                    // y = h_T @ W_hy + b_y
    float acc = by[t];
    const u16* hh = (const u16*)(hq + buf * 144);
#pragma unroll 8
    for (int k = 0; k < 256; ++k) {
      float hv = h2f(hh[((k >> 6) * 36 + ((k >> 1) & 31)) * 2 + (k & 1)]);
      acc += hv * Why[k * 128 + t];
    }
    out[b * 128 + t] = acc;
  }
}

extern "C" void kernel_launch(void* const* d_in, const int* in_sizes, int n_in,
                              void* d_out, int out_size, void* d_ws, size_t ws_size,
                              hipStream_t stream) {
  const float* x   = (const float*)d_in[0];
  const float* Wxi = (const float*)d_in[1];
  const float* Whi = (const float*)d_in[2];
  const float* b_i = (const float*)d_in[3];
  const float* Wxf = (const float*)d_in[4];
  const float* Whf = (const float*)d_in[5];
  const float* b_f = (const float*)d_in[6];
  const float* Wxg = (const float*)d_in[7];
  const float* Whg = (const float*)d_in[8];
  const float* b_g = (const float*)d_in[9];
  const float* Wxo = (const float*)d_in[10];
  const float* Who = (const float*)d_in[11];
  const float* b_o = (const float*)d_in[12];
  const float* Why = (const float*)d_in[13];
  const float* b_y = (const float*)d_in[14];
  float* out = (float*)d_out;

  int Tc = 256;
  while (Tc > 32 && (size_t)128 * Tc * 1024 * 2 + 1245184ull > ws_size) Tc >>= 1;
  const int tcShift = __builtin_ctz((unsigned)Tc);
  const int nch = 1024 / Tc;

  char* wsb = (char*)d_ws;
  const size_t gbytes = (size_t)128 * Tc * 1024 * 2;
  u16*   gates16 = (u16*)wsb;
  u16*   WxT     = (u16*)(wsb + gbytes);
  u32*   Whpp    = (u32*)(wsb + gbytes + 524288);
  u32*   h16s    = (u32*)(wsb + gbytes + 1048576);
  float* c_s     = (float*)(wsb + gbytes + 1048576 + 65536);

  const int recLds = 131072 + 1152 + 4096;
  (void)hipFuncSetAttribute((const void*)lstm_rec,
                            hipFuncAttributeMaxDynamicSharedMemorySize, recLds);

  lstm_prep<<<1728, 256, 0, stream>>>(Wxi, Wxf, Wxg, Wxo, Whi, Whf, Whg, Who,
                                      WxT, Whpp, h16s, c_s);
  for (int ci = 0; ci < nch; ++ci) {
    int t0 = ci * Tc;
    proj_gemm<<<dim3(Tc, 8), 256, 0, stream>>>(x, WxT, gates16, b_i, b_f, b_g, b_o,
                                               t0, tcShift);
    lstm_rec<<<128, 1024, recLds, stream>>>(Whpp, gates16, h16s, c_s, Why, b_y, out,
                                            Tc, (ci == nch - 1) ? 1 : 0);
  }
}